// Round 8
// baseline (245.289 us; speedup 1.0000x reference)
//
#include <hip/hip_runtime.h>
#include <math.h>

#define HW_ 4096
#define N_ 16384
#define RS2 1168  // LDS B-tile row stride: 18 ks * 64 B + 16 pad

typedef _Float16 f16x4 __attribute__((ext_vector_type(4)));
typedef _Float16 f16x8 __attribute__((ext_vector_type(8)));
typedef float f32x4 __attribute__((ext_vector_type(4)));

// ws layout (bytes):
//   Wt    f16 [4cb][18ks][256o][32c] @ 0          1,179,648
//         (c = cb*64 + (ks&1)*32 + cloc, k = ks>>1)
//   Woff  f16 [4cb][18ks][32d][32c]  @ 1,179,648    147,456
//   scale f32 [256]                  @ 1,327,104      1,024
//   shift f32 [256]                  @ 1,328,128      1,024
//   xT    f32 [4b][4096hw][256c]     @ 1,329,152 16,777,216
//   total 18,106,368

static __device__ __forceinline__ unsigned short f2h(float f) {
  _Float16 h = (_Float16)f;
  return __builtin_bit_cast(unsigned short, h);
}
static __device__ __forceinline__ f32x4 madv(f32x4 a, float s, f32x4 c) {
  c.x = fmaf(a.x, s, c.x);
  c.y = fmaf(a.y, s, c.y);
  c.z = fmaf(a.z, s, c.z);
  c.w = fmaf(a.w, s, c.w);
  return c;
}

// ---------- setup: x transpose (blocks 0..255) + weight prep (256..511) ----------
__global__ __launch_bounds__(512) void setup_kernel(
    const float* __restrict__ x, const float* __restrict__ weight,
    const float* __restrict__ w_off, const float* __restrict__ bias,
    const float* __restrict__ gamma, const float* __restrict__ beta,
    const float* __restrict__ rmean, const float* __restrict__ rvar,
    unsigned short* __restrict__ Wt, unsigned short* __restrict__ Woff,
    float* __restrict__ scale, float* __restrict__ shift, float* __restrict__ xT) {
  int bid = blockIdx.x;
  int tid = threadIdx.x;
  if (bid < 256) {  // one (b, image-row): transpose 256c x 64w, 16B/lane both sides
    __shared__ float t[64][65];
    int b = bid >> 6, h = bid & 63;
    int cq = tid & 15, cr = tid >> 4;  // cr 0..31
    for (int cg = 0; cg < 4; ++cg) {
      if (cg) __syncthreads();
#pragma unroll
      for (int hf = 0; hf < 2; ++hf) {
        int cc = cr + hf * 32;
        f32x4 v = *(const f32x4*)&x[(size_t)(b * 256 + cg * 64 + cc) * HW_ + h * 64 + cq * 4];
#pragma unroll
        for (int i2 = 0; i2 < 4; ++i2) t[cc][cq * 4 + i2] = v[i2];
      }
      __syncthreads();
#pragma unroll
      for (int hf = 0; hf < 2; ++hf) {
        int w2 = cr + hf * 32;
        f32x4 v;
#pragma unroll
        for (int i2 = 0; i2 < 4; ++i2) v[i2] = t[cq * 4 + i2][w2];
        *(f32x4*)&xT[(size_t)(b * HW_ + h * 64 + w2) * 256 + cg * 64 + cq * 4] = v;
      }
    }
    return;
  }
  int o = bid - 256;  // 0..255
  if (tid < 256) {
#pragma unroll
    for (int j = 0; j < 9; ++j) {
      int wk = tid + j * 256;  // 0..2303
      int cb = wk / 576;
      int rem = wk - cb * 576;
      int ks = rem >> 5, cloc = rem & 31;
      int c = cb * 64 + (ks & 1) * 32 + cloc;
      int k = ks >> 1;
      Wt[((cb * 18 + ks) * 256 + o) * 32 + cloc] = f2h(weight[(size_t)(o * 256 + c) * 9 + k]);
      if (o < 32) {
        float wv = (o < 27) ? w_off[(size_t)(o * 256 + c) * 9 + k] : 0.f;
        Woff[((cb * 18 + ks) * 32 + o) * 32 + cloc] = f2h(wv);
      }
    }
    if (o == 0) {
      float inv = rsqrtf(rvar[tid] + 1e-5f);
      float sc = gamma[tid] * inv;
      scale[tid] = sc;
      shift[tid] = beta[tid] + sc * (bias[tid] - rmean[tid]);
    }
  }
}

// ---------- fused: offset-conv MFMA -> pk/wgt in LDS -> sample+GEMM+BN+ReLU ----------
// 512 blocks (32 px each, 2 blocks/CU), 512 thr = 8 waves. K = 2304 in 4 chunks
// of 576 (64c x 9k -> 18 K-steps). Each wave owns a 32-o slice (M), nf covers 32 px.
__global__ __launch_bounds__(512, 4) void fused_kernel(
    const float* __restrict__ xT, const unsigned short* __restrict__ Wt,
    const unsigned short* __restrict__ Woff, const float* __restrict__ b_off,
    const float* __restrict__ scale, const float* __restrict__ shift,
    float* __restrict__ out) {
  __shared__ __align__(16) char smem[32 * RS2];          // 37,376 B
  float* om_lds = (float*)smem;                          // [32d][32px] (B-tile union)
  unsigned int* pk_lds = (unsigned int*)(smem + 4096);   // [9][32]
  float* w4_lds = (float*)(smem + 5248);                 // [9][32][4]

  int bid = blockIdx.x;
  int swz = (bid & 7) * 64 + (bid >> 3);  // XCD-chunked, bijective for 512
  int nbase = swz * 32;
  int b = nbase >> 12;
  int h = (nbase >> 6) & 63;
  int wb = nbase & 32;  // 0 or 32

  int tid = threadIdx.x;
  int lane = tid & 63;
  int wv = tid >> 6;
  int m15 = lane & 15, q = lane >> 4;
  int sn = tid >> 4;  // staging pixel 0..31
  int cs = tid & 15;  // staging 4-channel group (of 64c chunk)

  const char* xb = (const char*)xT + (size_t)b * (HW_ * 256 * 4);
  char* ldr = smem + sn * RS2 + ((cs >> 3) << 6) + (cs & 7) * 8;

  // ======== phase 1: offset conv om[27..32][32px] via MFMA (waves 0..3) ========
  int mf = (wv >> 1) & 1, nf1 = wv & 1;
  f32x4 aoff = (f32x4){0.f, 0.f, 0.f, 0.f};
  for (int cb = 0; cb < 4; ++cb) {
    {  // stage direct 3x3 patch chunk as f16 (64 c)
      const char* xc = xb + cb * 256 + cs * 16;
#pragma unroll
      for (int k = 0; k < 9; ++k) {
        int ky = k / 3, kx = k - 3 * (k / 3);
        int yy = h + ky - 1, xx = wb + sn + kx - 1;
        f32x4 v = (f32x4){0.f, 0.f, 0.f, 0.f};
        if (((unsigned)yy < 64u) && ((unsigned)xx < 64u))
          v = *(const f32x4*)(xc + (size_t)(yy * 64 + xx) * 1024);
        *(f16x4*)(ldr + k * 128) = __builtin_convertvector(v, f16x4);
      }
    }
    __syncthreads();
    if (wv < 4) {
#pragma unroll
      for (int ks = 0; ks < 18; ++ks) {
        f16x8 a = *(const f16x8*)(Woff + ((cb * 18 + ks) * 32 + mf * 16 + m15) * 32 + q * 8);
        f16x8 bb = *(const f16x8*)(smem + (nf1 * 16 + m15) * RS2 + ks * 64 + q * 16);
        aoff = __builtin_amdgcn_mfma_f32_16x16x32_f16(a, bb, aoff, 0, 0, 0);
      }
    }
    __syncthreads();
  }
  if (wv < 4) {
#pragma unroll
    for (int r = 0; r < 4; ++r)
      om_lds[(mf * 16 + q * 4 + r) * 32 + nf1 * 16 + m15] = aoff[r];
  }
  __syncthreads();

  // ======== phase 2: pk + bilinear*mask corner weights, in LDS ========
  if (tid < 288) {
    int k = tid >> 5, pxl = tid & 31;
    float dy = om_lds[k * 32 + pxl] + b_off[k];
    float dx = om_lds[(k + 9) * 32 + pxl] + b_off[k + 9];
    float z = om_lds[(k + 18) * 32 + pxl] + b_off[k + 18];
    float ms = 1.f / (1.f + expf(-z));
    int ky = k / 3, kx = k - 3 * ky;
    float py = dy + (float)(h - 1 + ky);
    float pxf = dx + (float)(wb + pxl - 1 + kx);
    float fy0 = floorf(py), fx0 = floorf(pxf);
    float ly = py - fy0, lx = pxf - fx0;
    int iy0 = (int)fy0, ix0 = (int)fx0;
    bool vy0 = (iy0 >= 0) && (iy0 < 64);
    bool vy1 = (iy0 >= -1) && (iy0 < 63);
    bool vx0 = (ix0 >= 0) && (ix0 < 64);
    bool vx1 = (ix0 >= -1) && (ix0 < 63);
    int yA = min(max(iy0, 0), 63), yB = min(max(iy0 + 1, 0), 63);
    int xA = min(max(ix0, 0), 63), xB = min(max(ix0 + 1, 0), 63);
    pk_lds[k * 32 + pxl] = (unsigned)(yA * 64 + xA) | ((unsigned)(xB - xA) << 12) |
                           ((unsigned)(yB - yA) << 13);
    float* wp = w4_lds + (k * 32 + pxl) * 4;
    wp[0] = (1.f - ly) * (1.f - lx) * ms * ((vy0 && vx0) ? 1.f : 0.f);
    wp[1] = (1.f - ly) * lx * ms * ((vy0 && vx1) ? 1.f : 0.f);
    wp[2] = ly * (1.f - lx) * ms * ((vy1 && vx0) ? 1.f : 0.f);
    wp[3] = ly * lx * ms * ((vy1 && vx1) ? 1.f : 0.f);
  }
  __syncthreads();

  // per-thread sampling params for its staging pixel
  unsigned int pkv[9];
  float wf[9][4];
#pragma unroll
  for (int k = 0; k < 9; ++k) {
    pkv[k] = pk_lds[k * 32 + sn];
#pragma unroll
    for (int j = 0; j < 4; ++j) wf[k][j] = w4_lds[(k * 32 + sn) * 4 + j];
  }

  // ======== phase 3: sample + main GEMM, register-pipelined staging ========
  f32x4 acc[2][2];
#pragma unroll
  for (int mfi = 0; mfi < 2; ++mfi)
#pragma unroll
    for (int nf = 0; nf < 2; ++nf) acc[mfi][nf] = (f32x4){0.f, 0.f, 0.f, 0.f};

  f16x4 sv[9];
#define GATHER(CB)                                                     \
  {                                                                    \
    const char* xc = xb + (CB) * 256 + cs * 16;                        \
    _Pragma("unroll") for (int k = 0; k < 9; ++k) {                    \
      unsigned pv = pkv[k];                                            \
      const char* p00 = xc + ((size_t)(pv & 0xFFFu) << 10);            \
      int dxb = (int)(pv & 0x1000u) >> 2;  /* 0 or 1024   */           \
      int dyb = (int)(pv & 0x2000u) << 3;  /* 0 or 65536  */           \
      f32x4 c00 = *(const f32x4*)(p00);                                \
      f32x4 c01 = *(const f32x4*)(p00 + dxb);                          \
      f32x4 c10 = *(const f32x4*)(p00 + dyb);                          \
      f32x4 c11 = *(const f32x4*)(p00 + dyb + dxb);                    \
      f32x4 v = (f32x4){0.f, 0.f, 0.f, 0.f};                           \
      v = madv(c00, wf[k][0], v);                                      \
      v = madv(c01, wf[k][1], v);                                      \
      v = madv(c10, wf[k][2], v);                                      \
      v = madv(c11, wf[k][3], v);                                      \
      sv[k] = __builtin_convertvector(v, f16x4);                       \
    }                                                                  \
  }

  GATHER(0);
  __syncthreads();  // pk/w4 register copies done before B-tile overwrite
  for (int cb = 0; cb < 4; ++cb) {
    {
#pragma unroll
      for (int k = 0; k < 9; ++k) *(f16x4*)(ldr + k * 128) = sv[k];
    }
    __syncthreads();
    if (cb < 3) GATHER(cb + 1);  // loads in flight under the MFMA block below
    {
      const unsigned short* wtk = Wt + (size_t)(cb * 18) * 8192 + (wv * 32 + m15) * 32 + q * 8;
#pragma unroll
      for (int ks = 0; ks < 18; ++ks) {
        const unsigned short* wp2 = wtk + ks * 8192;
        f16x8 a0 = *(const f16x8*)(wp2);
        f16x8 a1 = *(const f16x8*)(wp2 + 512);  // +16 o-rows
#pragma unroll
        for (int nf = 0; nf < 2; ++nf) {
          f16x8 bb = *(const f16x8*)(smem + (nf * 16 + m15) * RS2 + ks * 64 + q * 16);
          acc[0][nf] = __builtin_amdgcn_mfma_f32_16x16x32_f16(a0, bb, acc[0][nf], 0, 0, 0);
          acc[1][nf] = __builtin_amdgcn_mfma_f32_16x16x32_f16(a1, bb, acc[1][nf], 0, 0, 0);
        }
      }
    }
    __syncthreads();
  }

  // ======== epilogue: BN + ReLU; C/D: col=lane&15 (px), row=(lane>>4)*4+r (o) ========
  float* ob = out + (size_t)(b * 256) * HW_ + h * 64 + wb;
#pragma unroll
  for (int mfi = 0; mfi < 2; ++mfi)
#pragma unroll
    for (int r = 0; r < 4; ++r) {
      int o = wv * 32 + mfi * 16 + q * 4 + r;
      float sc = scale[o], sh = shift[o];
#pragma unroll
      for (int nf = 0; nf < 2; ++nf) {
        float vv = fmaxf(fmaf(acc[mfi][nf][r], sc, sh), 0.f);
        ob[(size_t)o * HW_ + nf * 16 + m15] = vv;
      }
    }
}

extern "C" void kernel_launch(void* const* d_in, const int* in_sizes, int n_in,
                              void* d_out, int out_size, void* d_ws, size_t ws_size,
                              hipStream_t stream) {
  (void)in_sizes; (void)n_in; (void)out_size; (void)ws_size;
  const float* x = (const float*)d_in[0];
  const float* w_off = (const float*)d_in[1];
  const float* b_off = (const float*)d_in[2];
  const float* weight = (const float*)d_in[3];
  const float* bias = (const float*)d_in[4];
  const float* gamma = (const float*)d_in[5];
  const float* beta = (const float*)d_in[6];
  const float* rmean = (const float*)d_in[7];
  const float* rvar = (const float*)d_in[8];
  char* ws = (char*)d_ws;
  unsigned short* Wt = (unsigned short*)ws;
  unsigned short* Woff = (unsigned short*)(ws + 1179648);
  float* scale = (float*)(ws + 1327104);
  float* shift = (float*)(ws + 1328128);
  float* xT = (float*)(ws + 1329152);
  float* out = (float*)d_out;

  setup_kernel<<<dim3(512), dim3(512), 0, stream>>>(x, weight, w_off, bias, gamma, beta,
                                                    rmean, rvar, Wt, Woff, scale, shift, xT);
  fused_kernel<<<dim3(512), dim3(512), 0, stream>>>(xT, Wt, Woff, b_off, scale, shift, out);
}

// Round 9
// 184.176 us; speedup vs baseline: 1.3318x; 1.3318x over previous
//
#include <hip/hip_runtime.h>
#include <math.h>

#define HW_ 4096
#define N_ 16384
#define RS2 1168     // LDS B-tile row stride: 18 ks * 64 B + 16 pad
#define LDS_PK 37376
#define LDS_W4 38528
#define LDS_TOT 43136

typedef _Float16 f16x4 __attribute__((ext_vector_type(4)));
typedef _Float16 f16x8 __attribute__((ext_vector_type(8)));
typedef float f32x4 __attribute__((ext_vector_type(4)));
typedef unsigned short u16x8 __attribute__((ext_vector_type(8)));

// ws layout (bytes):
//   Wt    f16 [4cb][18ks][256o][32c] @ 0          1,179,648
//         (c = cb*64 + (ks&1)*32 + cloc, k = ks>>1)
//   Woff  f16 [4cb][18ks][32d][32c]  @ 1,179,648    147,456
//   scale f32 [256]                  @ 1,327,104      1,024
//   shift f32 [256]                  @ 1,328,128      1,024
//   xT    f32 [4b][4096hw][256c]     @ 1,329,152 16,777,216
//   total 18,106,368

static __device__ __forceinline__ unsigned short f2h(float f) {
  _Float16 h = (_Float16)f;
  return __builtin_bit_cast(unsigned short, h);
}
static __device__ __forceinline__ f32x4 madv(f32x4 a, float s, f32x4 c) {
  c.x = fmaf(a.x, s, c.x);
  c.y = fmaf(a.y, s, c.y);
  c.z = fmaf(a.z, s, c.z);
  c.w = fmaf(a.w, s, c.w);
  return c;
}

// ---------- transpose x[b][c][hw] f32 -> xT[b][hw][c] f32 (1024 blocks, 256 thr) ----------
__global__ __launch_bounds__(256) void transp_kernel(const float* __restrict__ x,
                                                     float* __restrict__ xT) {
  __shared__ float t[64][65];
  int bid = blockIdx.x;
  int b = bid >> 8, cg = (bid >> 6) & 3, h = bid & 63;
  int tid = threadIdx.x;
  int l16 = tid & 15, r16 = tid >> 4;  // r16 0..15
  const float* xs = x + (size_t)(b * 256 + cg * 64) * HW_ + h * 64;
#pragma unroll
  for (int j = 0; j < 4; ++j) {
    int c = j * 16 + r16;
    f32x4 v = *(const f32x4*)(xs + (size_t)c * HW_ + l16 * 4);
    t[c][l16 * 4 + 0] = v.x;
    t[c][l16 * 4 + 1] = v.y;
    t[c][l16 * 4 + 2] = v.z;
    t[c][l16 * 4 + 3] = v.w;
  }
  __syncthreads();
  float* xd = xT + (size_t)(b * HW_ + h * 64) * 256 + cg * 64;
#pragma unroll
  for (int j = 0; j < 4; ++j) {
    int w2 = j * 16 + r16;
    f32x4 v;
#pragma unroll
    for (int i = 0; i < 4; ++i) v[i] = t[l16 * 4 + i][w2];
    *(f32x4*)(xd + (size_t)w2 * 256 + l16 * 4) = v;
  }
}

// ---------- weight prep (256 blocks = one o each, 256 thr) ----------
__global__ __launch_bounds__(256) void wprep_kernel(
    const float* __restrict__ weight, const float* __restrict__ w_off,
    const float* __restrict__ bias, const float* __restrict__ gamma,
    const float* __restrict__ beta, const float* __restrict__ rmean,
    const float* __restrict__ rvar, unsigned short* __restrict__ Wt,
    unsigned short* __restrict__ Woff, float* __restrict__ scale,
    float* __restrict__ shift) {
  int o = blockIdx.x, tid = threadIdx.x;
  __shared__ unsigned short wl[2304];
  __shared__ unsigned short wol[2304];
  const float* wrow = weight + (size_t)o * 2304;
  const float* worow = w_off + (size_t)o * 2304;  // dereferenced only when o<27
  bool do_off = (o < 32);
#pragma unroll
  for (int j = 0; j < 9; ++j) {
    int flat = tid + j * 256;  // = c*9 + k, coalesced read
    int c = flat / 9, k = flat - 9 * c;
    int cb = c >> 6, cloc = c & 31;
    int ks = (k << 1) | ((c >> 5) & 1);
    int dst = (cb * 18 + ks) * 32 + cloc;
    wl[dst] = f2h(wrow[flat]);
    if (do_off) wol[dst] = f2h((o < 27) ? worow[flat] : 0.f);
  }
  __syncthreads();
  // 72 chunks x 32 f16; 4 lanes x 16 B per chunk, 64 B contiguous per chunk
  for (int it = tid; it < 288; it += 256) {
    int chunk = it >> 2, part = it & 3;
    *(u16x8*)&Wt[((size_t)chunk * 256 + o) * 32 + part * 8] =
        *(const u16x8*)&wl[chunk * 32 + part * 8];
    if (do_off)
      *(u16x8*)&Woff[((size_t)chunk * 32 + o) * 32 + part * 8] =
          *(const u16x8*)&wol[chunk * 32 + part * 8];
  }
  if (o == 0) {
    float inv = rsqrtf(rvar[tid] + 1e-5f);
    float sc = gamma[tid] * inv;
    scale[tid] = sc;
    shift[tid] = beta[tid] + sc * (bias[tid] - rmean[tid]);
  }
}

// ---------- fused: offset-conv MFMA -> pk/wgt in LDS -> sample+GEMM+BN+ReLU ----------
// 512 blocks (32 px each), 512 thr = 8 waves. K = 2304 in 4 chunks of 576 (64c x 9k).
// pk/w4 live in a DEDICATED LDS region (no alias with B-tile) -> no persistent
// register arrays -> no spills (round-8 lesson: VGPR=64 + 186MB scratch writes).
__global__ __launch_bounds__(512) void fused_kernel(
    const float* __restrict__ xT, const unsigned short* __restrict__ Wt,
    const unsigned short* __restrict__ Woff, const float* __restrict__ b_off,
    const float* __restrict__ scale, const float* __restrict__ shift,
    float* __restrict__ out) {
  __shared__ __align__(16) char smem[LDS_TOT];           // 43,136 B -> <=3 blocks/CU by LDS
  float* om_lds = (float*)smem;                          // [32d][32px] aliases B-tile (ph1 only)
  unsigned int* pk_lds = (unsigned int*)(smem + LDS_PK); // [9][32]
  float* w4_lds = (float*)(smem + LDS_W4);               // [9][32][4]

  int bid = blockIdx.x;
  int swz = (bid & 7) * 64 + (bid >> 3);  // XCD-chunked, bijective for 512
  int nbase = swz * 32;
  int b = nbase >> 12;
  int h = (nbase >> 6) & 63;
  int wb = nbase & 32;  // 0 or 32

  int tid = threadIdx.x;
  int lane = tid & 63;
  int wv = tid >> 6;
  int m15 = lane & 15, q = lane >> 4;
  int sn = tid >> 4;  // staging pixel 0..31
  int cs = tid & 15;  // staging 4-channel group (of 64c chunk)

  const char* xb = (const char*)xT + (size_t)b * (HW_ * 256 * 4);
  char* ldr = smem + sn * RS2 + ((cs >> 3) << 6) + (cs & 7) * 8;

  // ======== phase 1: offset conv om[27..32][32px] via MFMA (waves 0..3) ========
  int mf = (wv >> 1) & 1, nf1 = wv & 1;
  f32x4 aoff = (f32x4){0.f, 0.f, 0.f, 0.f};
  for (int cb = 0; cb < 4; ++cb) {
    {  // stage direct 3x3 patch chunk as f16 (64 c)
      const char* xc = xb + cb * 256 + cs * 16;
#pragma unroll
      for (int k = 0; k < 9; ++k) {
        int ky = k / 3, kx = k - 3 * (k / 3);
        int yy = h + ky - 1, xx = wb + sn + kx - 1;
        f32x4 v = (f32x4){0.f, 0.f, 0.f, 0.f};
        if (((unsigned)yy < 64u) && ((unsigned)xx < 64u))
          v = *(const f32x4*)(xc + (size_t)(yy * 64 + xx) * 1024);
        *(f16x4*)(ldr + k * 128) = __builtin_convertvector(v, f16x4);
      }
    }
    __syncthreads();
    if (wv < 4) {
#pragma unroll
      for (int ks = 0; ks < 18; ++ks) {
        f16x8 a = *(const f16x8*)(Woff + ((cb * 18 + ks) * 32 + mf * 16 + m15) * 32 + q * 8);
        f16x8 bb = *(const f16x8*)(smem + (nf1 * 16 + m15) * RS2 + ks * 64 + q * 16);
        aoff = __builtin_amdgcn_mfma_f32_16x16x32_f16(a, bb, aoff, 0, 0, 0);
      }
    }
    __syncthreads();
  }
  if (wv < 4) {
#pragma unroll
    for (int r = 0; r < 4; ++r)
      om_lds[(mf * 16 + q * 4 + r) * 32 + nf1 * 16 + m15] = aoff[r];
  }
  __syncthreads();

  // ======== phase 2: pk + bilinear*mask corner weights -> dedicated LDS ========
  if (tid < 288) {
    int k = tid >> 5, pxl = tid & 31;
    float dy = om_lds[k * 32 + pxl] + b_off[k];
    float dx = om_lds[(k + 9) * 32 + pxl] + b_off[k + 9];
    float z = om_lds[(k + 18) * 32 + pxl] + b_off[k + 18];
    float ms = 1.f / (1.f + expf(-z));
    int ky = k / 3, kx = k - 3 * ky;
    float py = dy + (float)(h - 1 + ky);
    float pxf = dx + (float)(wb + pxl - 1 + kx);
    float fy0 = floorf(py), fx0 = floorf(pxf);
    float ly = py - fy0, lx = pxf - fx0;
    int iy0 = (int)fy0, ix0 = (int)fx0;
    bool vy0 = (iy0 >= 0) && (iy0 < 64);
    bool vy1 = (iy0 >= -1) && (iy0 < 63);
    bool vx0 = (ix0 >= 0) && (ix0 < 64);
    bool vx1 = (ix0 >= -1) && (ix0 < 63);
    int yA = min(max(iy0, 0), 63), yB = min(max(iy0 + 1, 0), 63);
    int xA = min(max(ix0, 0), 63), xB = min(max(ix0 + 1, 0), 63);
    pk_lds[k * 32 + pxl] = (unsigned)(yA * 64 + xA) | ((unsigned)(xB - xA) << 12) |
                           ((unsigned)(yB - yA) << 13);
    float* wp = w4_lds + (k * 32 + pxl) * 4;
    wp[0] = (1.f - ly) * (1.f - lx) * ms * ((vy0 && vx0) ? 1.f : 0.f);
    wp[1] = (1.f - ly) * lx * ms * ((vy0 && vx1) ? 1.f : 0.f);
    wp[2] = ly * (1.f - lx) * ms * ((vy1 && vx0) ? 1.f : 0.f);
    wp[3] = ly * lx * ms * ((vy1 && vx1) ? 1.f : 0.f);
  }
  __syncthreads();

  // ======== phase 3: sample + main GEMM, register-pipelined staging ========
  f32x4 acc[2][2];
#pragma unroll
  for (int mfi = 0; mfi < 2; ++mfi)
#pragma unroll
    for (int nf = 0; nf < 2; ++nf) acc[mfi][nf] = (f32x4){0.f, 0.f, 0.f, 0.f};

  f16x4 sv[9];
  // pk/w4 read from LDS each pass (broadcast reads) -- no persistent reg arrays
#define GATHER(CB)                                                     \
  {                                                                    \
    const char* xc = xb + (CB) * 256 + cs * 16;                        \
    _Pragma("unroll") for (int k = 0; k < 9; ++k) {                    \
      unsigned pv = pk_lds[k * 32 + sn];                               \
      f32x4 w4v = *(const f32x4*)(w4_lds + (k * 32 + sn) * 4);         \
      const char* p00 = xc + ((size_t)(pv & 0xFFFu) << 10);            \
      int dxb = (int)(pv & 0x1000u) >> 2;  /* 0 or 1024   */           \
      int dyb = (int)(pv & 0x2000u) << 3;  /* 0 or 65536  */           \
      f32x4 c00 = *(const f32x4*)(p00);                                \
      f32x4 c01 = *(const f32x4*)(p00 + dxb);                          \
      f32x4 c10 = *(const f32x4*)(p00 + dyb);                          \
      f32x4 c11 = *(const f32x4*)(p00 + dyb + dxb);                    \
      f32x4 v = (f32x4){0.f, 0.f, 0.f, 0.f};                           \
      v = madv(c00, w4v.x, v);                                         \
      v = madv(c01, w4v.y, v);                                         \
      v = madv(c10, w4v.z, v);                                         \
      v = madv(c11, w4v.w, v);                                         \
      sv[k] = __builtin_convertvector(v, f16x4);                       \
    }                                                                  \
  }

  GATHER(0);
  for (int cb = 0; cb < 4; ++cb) {
    {
#pragma unroll
      for (int k = 0; k < 9; ++k) *(f16x4*)(ldr + k * 128) = sv[k];
    }
    __syncthreads();
    if (cb < 3) GATHER(cb + 1);  // loads in flight under the MFMA block below
    {
      const unsigned short* wtk = Wt + (size_t)(cb * 18) * 8192 + (wv * 32 + m15) * 32 + q * 8;
#pragma unroll
      for (int ks = 0; ks < 18; ++ks) {
        const unsigned short* wp2 = wtk + ks * 8192;
        f16x8 a0 = *(const f16x8*)(wp2);
        f16x8 a1 = *(const f16x8*)(wp2 + 512);  // +16 o-rows
#pragma unroll
        for (int nf = 0; nf < 2; ++nf) {
          f16x8 bb = *(const f16x8*)(smem + (nf * 16 + m15) * RS2 + ks * 64 + q * 16);
          acc[0][nf] = __builtin_amdgcn_mfma_f32_16x16x32_f16(a0, bb, acc[0][nf], 0, 0, 0);
          acc[1][nf] = __builtin_amdgcn_mfma_f32_16x16x32_f16(a1, bb, acc[1][nf], 0, 0, 0);
        }
      }
    }
    __syncthreads();
  }

  // ======== epilogue: BN + ReLU; C/D: col=lane&15 (px), row=(lane>>4)*4+r (o) ========
  float* ob = out + (size_t)(b * 256) * HW_ + h * 64 + wb;
#pragma unroll
  for (int mfi = 0; mfi < 2; ++mfi)
#pragma unroll
    for (int r = 0; r < 4; ++r) {
      int o = wv * 32 + mfi * 16 + q * 4 + r;
      float sc = scale[o], sh = shift[o];
#pragma unroll
      for (int nf = 0; nf < 2; ++nf) {
        float vv = fmaxf(fmaf(acc[mfi][nf][r], sc, sh), 0.f);
        ob[(size_t)o * HW_ + nf * 16 + m15] = vv;
      }
    }
}

extern "C" void kernel_launch(void* const* d_in, const int* in_sizes, int n_in,
                              void* d_out, int out_size, void* d_ws, size_t ws_size,
                              hipStream_t stream) {
  (void)in_sizes; (void)n_in; (void)out_size; (void)ws_size;
  const float* x = (const float*)d_in[0];
  const float* w_off = (const float*)d_in[1];
  const float* b_off = (const float*)d_in[2];
  const float* weight = (const float*)d_in[3];
  const float* bias = (const float*)d_in[4];
  const float* gamma = (const float*)d_in[5];
  const float* beta = (const float*)d_in[6];
  const float* rmean = (const float*)d_in[7];
  const float* rvar = (const float*)d_in[8];
  char* ws = (char*)d_ws;
  unsigned short* Wt = (unsigned short*)ws;
  unsigned short* Woff = (unsigned short*)(ws + 1179648);
  float* scale = (float*)(ws + 1327104);
  float* shift = (float*)(ws + 1328128);
  float* xT = (float*)(ws + 1329152);
  float* out = (float*)d_out;

  transp_kernel<<<dim3(1024), dim3(256), 0, stream>>>(x, xT);
  wprep_kernel<<<dim3(256), dim3(256), 0, stream>>>(weight, w_off, bias, gamma, beta,
                                                    rmean, rvar, Wt, Woff, scale, shift);
  fused_kernel<<<dim3(512), dim3(512), 0, stream>>>(xT, Wt, Woff, b_off, scale, shift, out);
}